// Round 7
// baseline (384.388 us; speedup 1.0000x reference)
//
#include <hip/hip_runtime.h>
#include <hip/hip_bf16.h>
#include <math.h>

#define NN 50000
#define EE 800000
#define FIN 128
#define FOUT 32
#define HEADS 8
#define NT 16
#define HF 256          // HEADS*FOUT
#define TH (NT*HEADS)   // 128
#define CMAX 128        // max per-node degree held in LDS (Poisson(16) max ~45)
#define WCOLS 400       // 256 nf + 128 nt + 8 a1 + 8 pad

typedef __attribute__((ext_vector_type(8))) short bf16x8;
typedef __attribute__((ext_vector_type(4))) float f32x4;

static __device__ __forceinline__ unsigned short f2b(float f) {
    __hip_bfloat16 h = __float2bfloat16(f);
    return *reinterpret_cast<unsigned short*>(&h);
}

// ---- Prep: x -> bf16; tail block builds Wall^T [WCOLS][FIN] bf16 ----
// Wall cols: [0,256) = fc_w^T; [256,384) = W2 (nt); [384,392) = w1 (a1); [392,400) = 0
#define XQ (NN * FIN / 4)   // 1,600,000 uint2 outputs
#define XB (XQ / 256)       // 6250 blocks exactly
__global__ __launch_bounds__(256) void k_prep(
    const float* __restrict__ x, const float* __restrict__ fc_w,
    const float* __restrict__ attn_l, const float* __restrict__ attn_r,
    unsigned short* __restrict__ xh, unsigned short* __restrict__ wall)
{
    const int t = threadIdx.x;
    if (blockIdx.x < XB) {
        int i = blockIdx.x * 256 + t;
        float4 v = ((const float4*)x)[i];
        uint2 o;
        o.x = (unsigned)f2b(v.x) | ((unsigned)f2b(v.y) << 16);
        o.y = (unsigned)f2b(v.z) | ((unsigned)f2b(v.w) << 16);
        ((uint2*)xh)[i] = o;
        return;
    }
    // ---- Wall build (single tail block) ----
    // part 1: fc_w^T  (reads coalesced across t)
    for (int k = 0; k < FIN; k++)
        wall[t * FIN + k] = f2b(fc_w[k * HF + t]);
    // part 2: W2[k, rem] = sum_f fc_w[k, f*8+h] * attn_r[tt, f, h];  rem = tt*8+h
    {
        int rem = t & 127, kh = t >> 7;
        int tt = rem >> 3, h = rem & 7;
        for (int k = kh * 64; k < kh * 64 + 64; k++) {
            float s = 0.f;
#pragma unroll
            for (int f = 0; f < FOUT; f++)
                s += fc_w[k * HF + f * HEADS + h] * attn_r[(tt * FOUT + f) * HEADS + h];
            wall[(256 + rem) * FIN + k] = f2b(s);
        }
    }
    // part 3: w1[k, h] = sum_f fc_w[k, f*8+h] * attn_l[f, h]
    for (int i = t; i < 8 * FIN; i += 256) {
        int hh = i >> 7, k = i & 127;
        float s = 0.f;
#pragma unroll
        for (int f = 0; f < FOUT; f++)
            s += fc_w[k * HF + f * HEADS + hh] * attn_l[f * HEADS + hh];
        wall[(384 + hh) * FIN + k] = f2b(s);
    }
    // part 4: zero pad cols 392..399
    for (int i = t; i < 8 * FIN; i += 256)
        wall[392 * FIN + i] = 0;
}

// ---- MFMA GEMM: [N,128] @ Wall [128,400] -> nf(bf16) + nt(f32) + a1(f32) ----
// Block = 4 waves sharing one 16-node group; wave w does col-tiles w, w+4, ...
// No LDS, outputs written straight from accumulators.
__global__ __launch_bounds__(256) void k_gemm(
    const unsigned short* __restrict__ xh, const unsigned short* __restrict__ wall,
    unsigned short* __restrict__ nfh, float* __restrict__ a1,
    float* __restrict__ nt)
{
    const int w    = threadIdx.x >> 6;
    const int lane = threadIdx.x & 63;
    const int node0 = blockIdx.x * 16;          // NN % 16 == 0, no bounds checks
    const int mrow = lane & 15;
    const int kg   = lane >> 4;

    bf16x8 afr[4];
    const int arow = node0 + mrow;
#pragma unroll
    for (int kc = 0; kc < 4; kc++)
        afr[kc] = *(const bf16x8*)&xh[(size_t)arow * FIN + kc * 32 + kg * 8];

    const int row = kg * 4;
    for (int ct = w; ct < 25; ct += 4) {
        f32x4 acc = {0.f, 0.f, 0.f, 0.f};
#pragma unroll
        for (int kc = 0; kc < 4; kc++) {
            bf16x8 bfr = *(const bf16x8*)&wall[(ct * 16 + mrow) * FIN + kc * 32 + kg * 8];
            acc = __builtin_amdgcn_mfma_f32_16x16x32_bf16(afr[kc], bfr, acc, 0, 0, 0);
        }
        if (ct < 16) {          // nf: pack bf16 pairs, even lanes write u32
#pragma unroll
            for (int r = 0; r < 4; r++) {
                float o = __shfl_xor(acc[r], 1, 64);
                if (!(lane & 1)) {
                    unsigned pk = (unsigned)f2b(acc[r]) | ((unsigned)f2b(o) << 16);
                    *(unsigned*)&nfh[(size_t)(node0 + row + r) * HF + ct * 16 + mrow] = pk;
                }
            }
        } else if (ct < 24) {   // nt: f32 coalesced
#pragma unroll
            for (int r = 0; r < 4; r++)
                nt[(node0 + row + r) * TH + (ct - 16) * 16 + mrow] = acc[r];
        } else {                // a1 (cols 384..391), pad cols ignored
#pragma unroll
            for (int r = 0; r < 4; r++)
                if (mrow < 8) a1[(node0 + row + r) * HEADS + mrow] = acc[r];
        }
    }
}

// ---- CSR build: histogram of dst ----
__global__ __launch_bounds__(256) void k_hist(
    const int* __restrict__ dst, int* __restrict__ deg)
{
    int e = blockIdx.x * 256 + threadIdx.x;
    if (e >= EE) return;
    atomicAdd(&deg[dst[e]], 1);
}

// ---- CSR build: single-block exclusive scan deg -> rowptr[NN+1] ----
#define SCAN_T 1024
__global__ __launch_bounds__(1024) void k_scan(
    const int* __restrict__ deg, int* __restrict__ rowptr)
{
    __shared__ int part[SCAN_T];
    const int t = threadIdx.x;
    const int CH = (NN + SCAN_T - 1) / SCAN_T;  // 49
    int begin = t * CH;
    int end = begin + CH; if (end > NN) end = NN;
    if (begin > NN) begin = NN;
    int s = 0;
    for (int i = begin; i < end; i++) s += deg[i];
    part[t] = s;
    __syncthreads();
    for (int off = 1; off < SCAN_T; off <<= 1) {
        int v = (t >= off) ? part[t - off] : 0;
        __syncthreads();
        part[t] += v;
        __syncthreads();
    }
    int excl = (t == 0) ? 0 : part[t - 1];
    for (int i = begin; i < end; i++) {
        rowptr[i] = excl;
        excl += deg[i];
    }
    if (t == SCAN_T - 1) rowptr[NN] = EE;
}

// ---- CSR build: scatter records {e, src*TH+etype*HEADS}; deg doubles as cursor ----
__global__ __launch_bounds__(256) void k_scatter(
    const int* __restrict__ dst, const int* __restrict__ src,
    const int* __restrict__ et, const int* __restrict__ rowptr,
    int* __restrict__ deg, int2* __restrict__ recs)
{
    int e = blockIdx.x * 256 + threadIdx.x;
    if (e >= EE) return;
    int d = dst[e];
    int pos = atomicAdd(&deg[d], -1) - 1;      // unique slot deg-1..0
    int2 rec;
    rec.x = e;
    rec.y = src[e] * TH + et[e] * HEADS;
    recs[rowptr[d] + pos] = rec;
}

// ---- Fused per-node kernel: logits+exp, softmax denom in regs,
//      gather-aggregate, attn write, bias/mean/ELU epilogue ----
__global__ __launch_bounds__(256) void k_agg(
    const unsigned short* __restrict__ nfh, const float* __restrict__ a1,
    const float* __restrict__ nt, const int2* __restrict__ recs,
    const int* __restrict__ rowptr, const float* __restrict__ bias,
    float* __restrict__ A, float* __restrict__ ret)
{
    __shared__ float exs[4][CMAX * HEADS];  // 16 KB
    __shared__ int   sbuf[4][CMAX];         // 2 KB
    __shared__ int   ebuf[4][CMAX];         // 2 KB
    const int w    = threadIdx.x >> 6;
    const int lane = threadIdx.x & 63;
    const int n = blockIdx.x * 4 + w;
    if (n >= NN) return;
    const int start = rowptr[n];
    const int cnt   = rowptr[n + 1] - start;
    const int h  = lane & 7;
    const int ei = lane >> 3;
    const int half = lane & 1;

    const float a1h = a1[n * HEADS + h];
    float denl = 0.f;
    float4 acc = make_float4(0.f, 0.f, 0.f, 0.f);

    for (int base = 0; base < cnt; base += CMAX) {
        const int c = (cnt - base < CMAX) ? (cnt - base) : CMAX;
        for (int p0 = 0; p0 < c; p0 += 8) {
            int p = p0 + ei;
            if (p < c) {
                int2 rec = recs[start + base + p];
                float a = a1h + nt[rec.y + h];
                a = (a > 0.f) ? a : 0.2f * a;
                float ex = expf(a);
                exs[w][p * HEADS + h] = ex;
                denl += ex;
                if (h == 0) { sbuf[w][p] = rec.y >> 7; ebuf[w][p] = rec.x; }
            }
        }
        asm volatile("s_waitcnt lgkmcnt(0)" ::: "memory");
        for (int p = 0; p < c; p++) {
            int s = sbuf[w][p];
            float4 ex4 = *(const float4*)(&exs[w][p * HEADS + half * 4]);
            uint2 u = *(const uint2*)(nfh + (size_t)s * HF + lane * 4);
            float vx = __uint_as_float(u.x << 16);
            float vy = __uint_as_float(u.x & 0xFFFF0000u);
            float vz = __uint_as_float(u.y << 16);
            float vw = __uint_as_float(u.y & 0xFFFF0000u);
            acc.x += vx * ex4.x; acc.y += vy * ex4.y;
            acc.z += vz * ex4.z; acc.w += vw * ex4.w;
        }
        asm volatile("s_waitcnt lgkmcnt(0)" ::: "memory");
    }

    float den = denl;
    den += __shfl_xor(den, 8, 64);
    den += __shfl_xor(den, 16, 64);
    den += __shfl_xor(den, 32, 64);
    const float inv = (den > 0.f) ? 1.f / den : 0.f;

    if (cnt <= CMAX) {
        for (int p0 = 0; p0 < cnt; p0 += 8) {
            int p = p0 + ei;
            if (p < cnt) A[ebuf[w][p] * HEADS + h] = exs[w][p * HEADS + h] * inv;
        }
    } else {
        for (int p0 = 0; p0 < cnt; p0 += 8) {
            int p = p0 + ei;
            if (p < cnt) {
                int2 rec = recs[start + p];
                float a = a1h + nt[rec.y + h];
                a = (a > 0.f) ? a : 0.2f * a;
                A[rec.x * HEADS + h] = expf(a) * inv;
            }
        }
    }

    float4 invc;
    invc.x = __shfl(inv, half * 4 + 0, 64);
    invc.y = __shfl(inv, half * 4 + 1, 64);
    invc.z = __shfl(inv, half * 4 + 2, 64);
    invc.w = __shfl(inv, half * 4 + 3, 64);
    float4 b = *(const float4*)(&bias[lane * 4]);
    acc.x = acc.x * invc.x + b.x;
    acc.y = acc.y * invc.y + b.y;
    acc.z = acc.z * invc.z + b.z;
    acc.w = acc.w * invc.w + b.w;

    for (int m = 8; m <= 32; m <<= 1) {
        acc.x += __shfl_xor(acc.x, m, 64);
        acc.y += __shfl_xor(acc.y, m, 64);
        acc.z += __shfl_xor(acc.z, m, 64);
        acc.w += __shfl_xor(acc.w, m, 64);
    }
    if (lane < 8) {
        float4 o;
        o.x = acc.x * 0.125f; o.y = acc.y * 0.125f;
        o.z = acc.z * 0.125f; o.w = acc.w * 0.125f;
        o.x = (o.x > 0.f) ? o.x : (expf(o.x) - 1.f);
        o.y = (o.y > 0.f) ? o.y : (expf(o.y) - 1.f);
        o.z = (o.z > 0.f) ? o.z : (expf(o.z) - 1.f);
        o.w = (o.w > 0.f) ? o.w : (expf(o.w) - 1.f);
        *(float4*)(&ret[n * FOUT + lane * 4]) = o;
    }
}

extern "C" void kernel_launch(void* const* d_in, const int* in_sizes, int n_in,
                              void* d_out, int out_size, void* d_ws, size_t ws_size,
                              hipStream_t stream)
{
    const float* x      = (const float*)d_in[0];
    const float* fc_w   = (const float*)d_in[1];
    const float* attn_l = (const float*)d_in[2];
    const float* attn_r = (const float*)d_in[3];
    const float* bias   = (const float*)d_in[4];
    const int*   src    = (const int*)d_in[5];
    const int*   dst    = (const int*)d_in[6];
    const int*   etype  = (const int*)d_in[7];

    float* out_attn = (float*)d_out;                 // [E, 1, HEADS]
    float* out_ret  = out_attn + (size_t)EE * HEADS; // [N, FOUT]

    // workspace layout (bytes)
    char* ws = (char*)d_ws;
    unsigned short* nfh = (unsigned short*)(ws);     // 25.6 MB
    float* a1     = (float*)(ws + 25600000);         // 1.6 MB
    float* nt     = (float*)(ws + 27200000);         // 25.6 MB
    int*   deg    = (int*)(ws + 52800000);           // 200 KB (also scatter cursor)
    int*   rowptr = (int*)(ws + 53000000);           // 200 KB + 4
    int2*  recs   = (int2*)(ws + 53200008);          // 6.4 MB
    unsigned short* xh   = (unsigned short*)(ws + 59600128);  // 12.8 MB
    unsigned short* wall = (unsigned short*)(ws + 72400128);  // 102.4 KB

    hipMemsetAsync(deg, 0, (size_t)NN * 4, stream);

    k_prep<<<XB + 1, 256, 0, stream>>>(x, fc_w, attn_l, attn_r, xh, wall);

    k_gemm<<<NN / 16, 256, 0, stream>>>(xh, wall, nfh, a1, nt);

    k_hist<<<(EE + 255) / 256, 256, 0, stream>>>(dst, deg);
    k_scan<<<1, SCAN_T, 0, stream>>>(deg, rowptr);
    k_scatter<<<(EE + 255) / 256, 256, 0, stream>>>(dst, src, etype, rowptr, deg, recs);

    k_agg<<<(NN + 3) / 4, 256, 0, stream>>>(nfh, a1, nt, recs, rowptr, bias,
                                            out_attn, out_ret);
}

// Round 8
// 297.974 us; speedup vs baseline: 1.2900x; 1.2900x over previous
//
#include <hip/hip_runtime.h>
#include <hip/hip_bf16.h>
#include <math.h>

#define NN 50000
#define EE 800000
#define FIN 128
#define FOUT 32
#define HEADS 8
#define NT 16
#define HF 256          // HEADS*FOUT
#define TH (NT*HEADS)   // 128
#define CMAX 128        // max per-node degree held in LDS (Poisson(16) max ~45)

typedef __attribute__((ext_vector_type(8))) short bf16x8;
typedef __attribute__((ext_vector_type(4))) float f32x4;

static __device__ __forceinline__ unsigned short f2b(float f) {
    __hip_bfloat16 h = __float2bfloat16(f);
    return *reinterpret_cast<unsigned short*>(&h);
}

// ---- Wall build (200 blocks, 1 thread/elem) + dst histogram (3125 blocks) ----
// Wall^T [400][128] bf16: cols [0,256)=fc_w^T; [256,384)=W2(nt); [384,392)=w1(a1); [392,400)=0
#define WBLK 200
#define HBLK (EE / 256)   // 3125 exactly
__global__ __launch_bounds__(256) void k_wallhist(
    const float* __restrict__ fc_w, const float* __restrict__ attn_l,
    const float* __restrict__ attn_r, const int* __restrict__ dst,
    unsigned short* __restrict__ wall, int* __restrict__ deg)
{
    const int b = blockIdx.x;
    if (b < WBLK) {
        int j = b * 256 + threadIdx.x;       // j = col*128 + k, j < 51200
        int col = j >> 7, k = j & 127;
        float s;
        if (col < 256) {
            s = fc_w[k * HF + col];
        } else if (col < 384) {
            int rem = col - 256, tt = rem >> 3, h = rem & 7;
            s = 0.f;
#pragma unroll
            for (int f = 0; f < FOUT; f++)
                s += fc_w[k * HF + f * HEADS + h] * attn_r[(tt * FOUT + f) * HEADS + h];
        } else if (col < 392) {
            int hh = col - 384;
            s = 0.f;
#pragma unroll
            for (int f = 0; f < FOUT; f++)
                s += fc_w[k * HF + f * HEADS + hh] * attn_l[f * HEADS + hh];
        } else {
            s = 0.f;
        }
        wall[j] = f2b(s);
    } else {
        int e = (b - WBLK) * 256 + threadIdx.x;
        atomicAdd(&deg[dst[e]], 1);
    }
}

// ---- CSR build: single-block exclusive scan deg -> rowptr[NN+1] ----
#define SCAN_T 1024
__global__ __launch_bounds__(1024) void k_scan(
    const int* __restrict__ deg, int* __restrict__ rowptr)
{
    __shared__ int part[SCAN_T];
    const int t = threadIdx.x;
    const int CH = (NN + SCAN_T - 1) / SCAN_T;  // 49
    int begin = t * CH;
    int end = begin + CH; if (end > NN) end = NN;
    if (begin > NN) begin = NN;
    int s = 0;
    for (int i = begin; i < end; i++) s += deg[i];
    part[t] = s;
    __syncthreads();
    for (int off = 1; off < SCAN_T; off <<= 1) {
        int v = (t >= off) ? part[t - off] : 0;
        __syncthreads();
        part[t] += v;
        __syncthreads();
    }
    int excl = (t == 0) ? 0 : part[t - 1];
    for (int i = begin; i < end; i++) {
        rowptr[i] = excl;
        excl += deg[i];
    }
    if (t == SCAN_T - 1) rowptr[NN] = EE;
}

// ---- CSR build: scatter records {e, src*TH+etype*HEADS}; deg doubles as cursor ----
__global__ __launch_bounds__(256) void k_scatter(
    const int* __restrict__ dst, const int* __restrict__ src,
    const int* __restrict__ et, const int* __restrict__ rowptr,
    int* __restrict__ deg, int2* __restrict__ recs)
{
    int e = blockIdx.x * 256 + threadIdx.x;
    if (e >= EE) return;
    int d = dst[e];
    int pos = atomicAdd(&deg[d], -1) - 1;      // unique slot deg-1..0
    int2 rec;
    rec.x = e;
    rec.y = src[e] * TH + et[e] * HEADS;
    recs[rowptr[d] + pos] = rec;
}

// ---- MFMA GEMM: [N,128] @ Wall [128,400] -> nf(bf16) + nt(f32) + a1(f32) ----
// Reads x f32 directly, converts to bf16 fragments in-register. No LDS.
// Block = 4 waves sharing one 16-node group; wave w does col-tiles w, w+4, ...
__global__ __launch_bounds__(256) void k_gemm(
    const float* __restrict__ x, const unsigned short* __restrict__ wall,
    unsigned short* __restrict__ nfh, float* __restrict__ a1,
    float* __restrict__ nt)
{
    const int w    = threadIdx.x >> 6;
    const int lane = threadIdx.x & 63;
    const int node0 = blockIdx.x * 16;          // NN % 16 == 0, no bounds checks
    const int mrow = lane & 15;
    const int kg   = lane >> 4;

    // A fragments from f32 x, converted in-register
    bf16x8 afr[4];
    const float* xrow = x + (size_t)(node0 + mrow) * FIN + kg * 8;
#pragma unroll
    for (int kc = 0; kc < 4; kc++) {
        float4 lo = *(const float4*)(xrow + kc * 32);
        float4 hi = *(const float4*)(xrow + kc * 32 + 4);
        union { bf16x8 v; unsigned short u[8]; } tmp;
        tmp.u[0] = f2b(lo.x); tmp.u[1] = f2b(lo.y);
        tmp.u[2] = f2b(lo.z); tmp.u[3] = f2b(lo.w);
        tmp.u[4] = f2b(hi.x); tmp.u[5] = f2b(hi.y);
        tmp.u[6] = f2b(hi.z); tmp.u[7] = f2b(hi.w);
        afr[kc] = tmp.v;
    }

    const int row = kg * 4;
    for (int ct = w; ct < 25; ct += 4) {
        f32x4 acc = {0.f, 0.f, 0.f, 0.f};
#pragma unroll
        for (int kc = 0; kc < 4; kc++) {
            bf16x8 bfr = *(const bf16x8*)&wall[(ct * 16 + mrow) * FIN + kc * 32 + kg * 8];
            acc = __builtin_amdgcn_mfma_f32_16x16x32_bf16(afr[kc], bfr, acc, 0, 0, 0);
        }
        if (ct < 16) {          // nf: pack bf16 pairs, even lanes write u32
#pragma unroll
            for (int r = 0; r < 4; r++) {
                float o = __shfl_xor(acc[r], 1, 64);
                if (!(lane & 1)) {
                    unsigned pk = (unsigned)f2b(acc[r]) | ((unsigned)f2b(o) << 16);
                    *(unsigned*)&nfh[(size_t)(node0 + row + r) * HF + ct * 16 + mrow] = pk;
                }
            }
        } else if (ct < 24) {   // nt: f32 coalesced
#pragma unroll
            for (int r = 0; r < 4; r++)
                nt[(node0 + row + r) * TH + (ct - 16) * 16 + mrow] = acc[r];
        } else {                // a1 (cols 384..391), pad cols ignored
#pragma unroll
            for (int r = 0; r < 4; r++)
                if (mrow < 8) a1[(node0 + row + r) * HEADS + mrow] = acc[r];
        }
    }
}

// ---- Fused per-node kernel: logits+exp, softmax denom in regs,
//      gather-aggregate, attn write, bias/mean/ELU epilogue ----
__global__ __launch_bounds__(256) void k_agg(
    const unsigned short* __restrict__ nfh, const float* __restrict__ a1,
    const float* __restrict__ nt, const int2* __restrict__ recs,
    const int* __restrict__ rowptr, const float* __restrict__ bias,
    float* __restrict__ A, float* __restrict__ ret)
{
    __shared__ float exs[4][CMAX * HEADS];  // 16 KB
    __shared__ int   sbuf[4][CMAX];         // 2 KB
    __shared__ int   ebuf[4][CMAX];         // 2 KB
    const int w    = threadIdx.x >> 6;
    const int lane = threadIdx.x & 63;
    const int n = blockIdx.x * 4 + w;
    if (n >= NN) return;
    const int start = rowptr[n];
    const int cnt   = rowptr[n + 1] - start;
    const int h  = lane & 7;
    const int ei = lane >> 3;
    const int half = lane & 1;

    const float a1h = a1[n * HEADS + h];
    float denl = 0.f;
    float4 acc = make_float4(0.f, 0.f, 0.f, 0.f);

    for (int base = 0; base < cnt; base += CMAX) {
        const int c = (cnt - base < CMAX) ? (cnt - base) : CMAX;
        for (int p0 = 0; p0 < c; p0 += 8) {
            int p = p0 + ei;
            if (p < c) {
                int2 rec = recs[start + base + p];
                float a = a1h + nt[rec.y + h];
                a = (a > 0.f) ? a : 0.2f * a;
                float ex = expf(a);
                exs[w][p * HEADS + h] = ex;
                denl += ex;
                if (h == 0) { sbuf[w][p] = rec.y >> 7; ebuf[w][p] = rec.x; }
            }
        }
        asm volatile("s_waitcnt lgkmcnt(0)" ::: "memory");
        for (int p = 0; p < c; p++) {
            int s = sbuf[w][p];
            float4 ex4 = *(const float4*)(&exs[w][p * HEADS + half * 4]);
            uint2 u = *(const uint2*)(nfh + (size_t)s * HF + lane * 4);
            float vx = __uint_as_float(u.x << 16);
            float vy = __uint_as_float(u.x & 0xFFFF0000u);
            float vz = __uint_as_float(u.y << 16);
            float vw = __uint_as_float(u.y & 0xFFFF0000u);
            acc.x += vx * ex4.x; acc.y += vy * ex4.y;
            acc.z += vz * ex4.z; acc.w += vw * ex4.w;
        }
        asm volatile("s_waitcnt lgkmcnt(0)" ::: "memory");
    }

    float den = denl;
    den += __shfl_xor(den, 8, 64);
    den += __shfl_xor(den, 16, 64);
    den += __shfl_xor(den, 32, 64);
    const float inv = (den > 0.f) ? 1.f / den : 0.f;

    if (cnt <= CMAX) {
        for (int p0 = 0; p0 < cnt; p0 += 8) {
            int p = p0 + ei;
            if (p < cnt) A[ebuf[w][p] * HEADS + h] = exs[w][p * HEADS + h] * inv;
        }
    } else {
        for (int p0 = 0; p0 < cnt; p0 += 8) {
            int p = p0 + ei;
            if (p < cnt) {
                int2 rec = recs[start + p];
                float a = a1h + nt[rec.y + h];
                a = (a > 0.f) ? a : 0.2f * a;
                A[rec.x * HEADS + h] = expf(a) * inv;
            }
        }
    }

    float4 invc;
    invc.x = __shfl(inv, half * 4 + 0, 64);
    invc.y = __shfl(inv, half * 4 + 1, 64);
    invc.z = __shfl(inv, half * 4 + 2, 64);
    invc.w = __shfl(inv, half * 4 + 3, 64);
    float4 b = *(const float4*)(&bias[lane * 4]);
    acc.x = acc.x * invc.x + b.x;
    acc.y = acc.y * invc.y + b.y;
    acc.z = acc.z * invc.z + b.z;
    acc.w = acc.w * invc.w + b.w;

    for (int m = 8; m <= 32; m <<= 1) {
        acc.x += __shfl_xor(acc.x, m, 64);
        acc.y += __shfl_xor(acc.y, m, 64);
        acc.z += __shfl_xor(acc.z, m, 64);
        acc.w += __shfl_xor(acc.w, m, 64);
    }
    if (lane < 8) {
        float4 o;
        o.x = acc.x * 0.125f; o.y = acc.y * 0.125f;
        o.z = acc.z * 0.125f; o.w = acc.w * 0.125f;
        o.x = (o.x > 0.f) ? o.x : (expf(o.x) - 1.f);
        o.y = (o.y > 0.f) ? o.y : (expf(o.y) - 1.f);
        o.z = (o.z > 0.f) ? o.z : (expf(o.z) - 1.f);
        o.w = (o.w > 0.f) ? o.w : (expf(o.w) - 1.f);
        *(float4*)(&ret[n * FOUT + lane * 4]) = o;
    }
}

extern "C" void kernel_launch(void* const* d_in, const int* in_sizes, int n_in,
                              void* d_out, int out_size, void* d_ws, size_t ws_size,
                              hipStream_t stream)
{
    const float* x      = (const float*)d_in[0];
    const float* fc_w   = (const float*)d_in[1];
    const float* attn_l = (const float*)d_in[2];
    const float* attn_r = (const float*)d_in[3];
    const float* bias   = (const float*)d_in[4];
    const int*   src    = (const int*)d_in[5];
    const int*   dst    = (const int*)d_in[6];
    const int*   etype  = (const int*)d_in[7];

    float* out_attn = (float*)d_out;                 // [E, 1, HEADS]
    float* out_ret  = out_attn + (size_t)EE * HEADS; // [N, FOUT]

    // workspace layout (bytes)
    char* ws = (char*)d_ws;
    unsigned short* nfh = (unsigned short*)(ws);     // 25.6 MB
    float* a1     = (float*)(ws + 25600000);         // 1.6 MB
    float* nt     = (float*)(ws + 27200000);         // 25.6 MB
    int*   deg    = (int*)(ws + 52800000);           // 200 KB (also scatter cursor)
    int*   rowptr = (int*)(ws + 53000000);           // 200 KB + 4
    int2*  recs   = (int2*)(ws + 53200008);          // 6.4 MB
    unsigned short* wall = (unsigned short*)(ws + 59600128);  // 102.4 KB

    hipMemsetAsync(deg, 0, (size_t)NN * 4, stream);

    k_wallhist<<<WBLK + HBLK, 256, 0, stream>>>(fc_w, attn_l, attn_r, dst, wall, deg);

    k_scan<<<1, SCAN_T, 0, stream>>>(deg, rowptr);
    k_scatter<<<(EE + 255) / 256, 256, 0, stream>>>(dst, src, etype, rowptr, deg, recs);

    k_gemm<<<NN / 16, 256, 0, stream>>>(x, wall, nfh, a1, nt);

    k_agg<<<(NN + 3) / 4, 256, 0, stream>>>(nfh, a1, nt, recs, rowptr, bias,
                                            out_attn, out_ret);
}

// Round 9
// 191.916 us; speedup vs baseline: 2.0029x; 1.5526x over previous
//
#include <hip/hip_runtime.h>
#include <hip/hip_bf16.h>
#include <math.h>

#define NN 50000
#define EE 800000
#define FIN 128
#define FOUT 32
#define HEADS 8
#define NT 16
#define HF 256          // HEADS*FOUT
#define TH (NT*HEADS)   // 128
#define CMAX 128        // max per-node degree held in LDS (Poisson(16) max ~45)

typedef __attribute__((ext_vector_type(8))) short bf16x8;
typedef __attribute__((ext_vector_type(4))) float f32x4;

static __device__ __forceinline__ unsigned short f2b(float f) {
    __hip_bfloat16 h = __float2bfloat16(f);
    return *reinterpret_cast<unsigned short*>(&h);
}

static __device__ __forceinline__ void fma_edge(float4& acc, uint2 u, float4 e) {
    acc.x += __uint_as_float(u.x << 16)          * e.x;
    acc.y += __uint_as_float(u.x & 0xFFFF0000u) * e.y;
    acc.z += __uint_as_float(u.y << 16)          * e.z;
    acc.w += __uint_as_float(u.y & 0xFFFF0000u) * e.w;
}

// ---- Wall build (200 blocks) + dst histogram (3125 blocks) ----
// Wall^T [400][128] bf16: cols [0,256)=fc_w^T; [256,384)=W2(nt); [384,392)=w1(a1); [392,400)=0
#define WBLK 200
#define HBLK (EE / 256)       // 3125
#define GBLK ((NN + 63) / 64) // 782
#define ABLK ((NN + 255) / 256)
__global__ __launch_bounds__(256) void k_wallhist(
    const float* __restrict__ fc_w, const float* __restrict__ attn_l,
    const float* __restrict__ attn_r, const int* __restrict__ dst,
    unsigned short* __restrict__ wall, int* __restrict__ deg)
{
    const int b = blockIdx.x;
    if (b < WBLK) {
        int j = b * 256 + threadIdx.x;       // j = col*128 + k, j < 51200
        int col = j >> 7, k = j & 127;
        float s;
        if (col < 256) {
            s = fc_w[k * HF + col];
        } else if (col < 384) {
            int rem = col - 256, tt = rem >> 3, h = rem & 7;
            s = 0.f;
#pragma unroll
            for (int f = 0; f < FOUT; f++)
                s += fc_w[k * HF + f * HEADS + h] * attn_r[(tt * FOUT + f) * HEADS + h];
        } else if (col < 392) {
            int hh = col - 384;
            s = 0.f;
#pragma unroll
            for (int f = 0; f < FOUT; f++)
                s += fc_w[k * HF + f * HEADS + hh] * attn_l[f * HEADS + hh];
        } else {
            s = 0.f;
        }
        wall[j] = f2b(s);
    } else {
        int e = (b - WBLK) * 256 + threadIdx.x;
        atomicAdd(&deg[dst[e]], 1);
    }
}

// ---- CSR alloc: rowptr[n] = bump-allocated segment base (placement arbitrary) ----
__global__ __launch_bounds__(256) void k_alloc(
    const int* __restrict__ deg, int* __restrict__ counter,
    int* __restrict__ rowptr)
{
    int n = blockIdx.x * 256 + threadIdx.x;
    if (n < NN) rowptr[n] = atomicAdd(counter, deg[n]);
}

// ---- Fused: MFMA GEMM (blocks 0..GBLK) + edge scatter (blocks GBLK..) ----
// GEMM: [N,128] @ Wall [128,400] -> nf(bf16) + nt(f32) + a1(f32).
// Wave owns 16 nodes, all 25 col-tiles; x read f32, converted in-register.
__global__ __launch_bounds__(256) void k_scatgemm(
    const float* __restrict__ x, const unsigned short* __restrict__ wall,
    unsigned short* __restrict__ nfh, float* __restrict__ a1,
    float* __restrict__ nt,
    const int* __restrict__ dst, const int* __restrict__ src,
    const int* __restrict__ et, const int* __restrict__ rowptr,
    int* __restrict__ cursor, int2* __restrict__ recs)
{
    if (blockIdx.x >= GBLK) {
        int e = (blockIdx.x - GBLK) * 256 + threadIdx.x;  // exactly EE threads
        int d = dst[e];
        int pos = atomicAdd(&cursor[d], 1);
        int2 rec;
        rec.x = e;
        rec.y = src[e] * TH + et[e] * HEADS;
        recs[rowptr[d] + pos] = rec;
        return;
    }
    const int w    = threadIdx.x >> 6;
    const int lane = threadIdx.x & 63;
    const int node0 = blockIdx.x * 64 + w * 16;
    if (node0 >= NN) return;                    // only trims waves of last block
    const int mrow = lane & 15;
    const int kg   = lane >> 4;

    bf16x8 afr[4];
    const float* xrow = x + (size_t)(node0 + mrow) * FIN + kg * 8;
#pragma unroll
    for (int kc = 0; kc < 4; kc++) {
        float4 lo = *(const float4*)(xrow + kc * 32);
        float4 hi = *(const float4*)(xrow + kc * 32 + 4);
        union { bf16x8 v; unsigned short u[8]; } tmp;
        tmp.u[0] = f2b(lo.x); tmp.u[1] = f2b(lo.y);
        tmp.u[2] = f2b(lo.z); tmp.u[3] = f2b(lo.w);
        tmp.u[4] = f2b(hi.x); tmp.u[5] = f2b(hi.y);
        tmp.u[6] = f2b(hi.z); tmp.u[7] = f2b(hi.w);
        afr[kc] = tmp.v;
    }

    const int row = kg * 4;
#pragma unroll
    for (int ct = 0; ct < 25; ct++) {
        f32x4 acc = {0.f, 0.f, 0.f, 0.f};
#pragma unroll
        for (int kc = 0; kc < 4; kc++) {
            bf16x8 bfr = *(const bf16x8*)&wall[(ct * 16 + mrow) * FIN + kc * 32 + kg * 8];
            acc = __builtin_amdgcn_mfma_f32_16x16x32_bf16(afr[kc], bfr, acc, 0, 0, 0);
        }
        if (ct < 16) {          // nf: pack bf16 pairs, even lanes write u32
#pragma unroll
            for (int r = 0; r < 4; r++) {
                float o = __shfl_xor(acc[r], 1, 64);
                if (!(lane & 1)) {
                    unsigned pk = (unsigned)f2b(acc[r]) | ((unsigned)f2b(o) << 16);
                    *(unsigned*)&nfh[(size_t)(node0 + row + r) * HF + ct * 16 + mrow] = pk;
                }
            }
        } else if (ct < 24) {   // nt: f32 coalesced
#pragma unroll
            for (int r = 0; r < 4; r++)
                nt[(node0 + row + r) * TH + (ct - 16) * 16 + mrow] = acc[r];
        } else {                // a1 (cols 384..391), pad cols ignored
#pragma unroll
            for (int r = 0; r < 4; r++)
                if (mrow < 8) a1[(node0 + row + r) * HEADS + mrow] = acc[r];
        }
    }
}

// ---- Fused per-node kernel: logits+exp, softmax denom in regs,
//      gather-aggregate (4x unrolled), attn write, bias/mean/ELU epilogue ----
__global__ __launch_bounds__(256) void k_agg(
    const unsigned short* __restrict__ nfh, const float* __restrict__ a1,
    const float* __restrict__ nt, const int2* __restrict__ recs,
    const int* __restrict__ rowptr, const int* __restrict__ deg,
    const float* __restrict__ bias, float* __restrict__ A,
    float* __restrict__ ret)
{
    __shared__ __align__(16) float exs[4][CMAX * HEADS];  // 16 KB
    __shared__ __align__(16) int   sbuf[4][CMAX];         // 2 KB
    __shared__ __align__(16) int   ebuf[4][CMAX];         // 2 KB
    const int w    = threadIdx.x >> 6;
    const int lane = threadIdx.x & 63;
    const int n = blockIdx.x * 4 + w;
    if (n >= NN) return;
    const int start = rowptr[n];
    const int cnt   = deg[n];
    const int h  = lane & 7;
    const int ei = lane >> 3;
    const int half = lane & 1;

    const float a1h = a1[n * HEADS + h];
    float denl = 0.f;
    float4 acc = make_float4(0.f, 0.f, 0.f, 0.f);

    for (int base = 0; base < cnt; base += CMAX) {
        const int c = (cnt - base < CMAX) ? (cnt - base) : CMAX;
        for (int p0 = 0; p0 < c; p0 += 8) {
            int p = p0 + ei;
            if (p < c) {
                int2 rec = recs[start + base + p];
                float a = a1h + nt[rec.y + h];
                a = (a > 0.f) ? a : 0.2f * a;
                float ex = expf(a);
                exs[w][p * HEADS + h] = ex;
                denl += ex;
                if (h == 0) { sbuf[w][p] = rec.y >> 7; ebuf[w][p] = rec.x; }
            }
        }
        asm volatile("s_waitcnt lgkmcnt(0)" ::: "memory");
        int p = 0;
        for (; p + 4 <= c; p += 4) {
            int4 ss = *(const int4*)&sbuf[w][p];
            uint2 u0 = *(const uint2*)(nfh + (size_t)ss.x * HF + lane * 4);
            uint2 u1 = *(const uint2*)(nfh + (size_t)ss.y * HF + lane * 4);
            uint2 u2 = *(const uint2*)(nfh + (size_t)ss.z * HF + lane * 4);
            uint2 u3 = *(const uint2*)(nfh + (size_t)ss.w * HF + lane * 4);
            float4 e0 = *(const float4*)&exs[w][(p + 0) * HEADS + half * 4];
            float4 e1 = *(const float4*)&exs[w][(p + 1) * HEADS + half * 4];
            float4 e2 = *(const float4*)&exs[w][(p + 2) * HEADS + half * 4];
            float4 e3 = *(const float4*)&exs[w][(p + 3) * HEADS + half * 4];
            fma_edge(acc, u0, e0);
            fma_edge(acc, u1, e1);
            fma_edge(acc, u2, e2);
            fma_edge(acc, u3, e3);
        }
        for (; p < c; p++) {
            int s = sbuf[w][p];
            uint2 u = *(const uint2*)(nfh + (size_t)s * HF + lane * 4);
            float4 e = *(const float4*)&exs[w][p * HEADS + half * 4];
            fma_edge(acc, u, e);
        }
        asm volatile("s_waitcnt lgkmcnt(0)" ::: "memory");
    }

    float den = denl;
    den += __shfl_xor(den, 8, 64);
    den += __shfl_xor(den, 16, 64);
    den += __shfl_xor(den, 32, 64);
    const float inv = (den > 0.f) ? 1.f / den : 0.f;

    if (cnt <= CMAX) {
        for (int p0 = 0; p0 < cnt; p0 += 8) {
            int p = p0 + ei;
            if (p < cnt) A[ebuf[w][p] * HEADS + h] = exs[w][p * HEADS + h] * inv;
        }
    } else {
        for (int p0 = 0; p0 < cnt; p0 += 8) {
            int p = p0 + ei;
            if (p < cnt) {
                int2 rec = recs[start + p];
                float a = a1h + nt[rec.y + h];
                a = (a > 0.f) ? a : 0.2f * a;
                A[rec.x * HEADS + h] = expf(a) * inv;
            }
        }
    }

    float4 invc;
    invc.x = __shfl(inv, half * 4 + 0, 64);
    invc.y = __shfl(inv, half * 4 + 1, 64);
    invc.z = __shfl(inv, half * 4 + 2, 64);
    invc.w = __shfl(inv, half * 4 + 3, 64);
    float4 b = *(const float4*)(&bias[lane * 4]);
    acc.x = acc.x * invc.x + b.x;
    acc.y = acc.y * invc.y + b.y;
    acc.z = acc.z * invc.z + b.z;
    acc.w = acc.w * invc.w + b.w;

    for (int m = 8; m <= 32; m <<= 1) {
        acc.x += __shfl_xor(acc.x, m, 64);
        acc.y += __shfl_xor(acc.y, m, 64);
        acc.z += __shfl_xor(acc.z, m, 64);
        acc.w += __shfl_xor(acc.w, m, 64);
    }
    if (lane < 8) {
        float4 o;
        o.x = acc.x * 0.125f; o.y = acc.y * 0.125f;
        o.z = acc.z * 0.125f; o.w = acc.w * 0.125f;
        o.x = (o.x > 0.f) ? o.x : (expf(o.x) - 1.f);
        o.y = (o.y > 0.f) ? o.y : (expf(o.y) - 1.f);
        o.z = (o.z > 0.f) ? o.z : (expf(o.z) - 1.f);
        o.w = (o.w > 0.f) ? o.w : (expf(o.w) - 1.f);
        *(float4*)(&ret[n * FOUT + lane * 4]) = o;
    }
}

extern "C" void kernel_launch(void* const* d_in, const int* in_sizes, int n_in,
                              void* d_out, int out_size, void* d_ws, size_t ws_size,
                              hipStream_t stream)
{
    const float* x      = (const float*)d_in[0];
    const float* fc_w   = (const float*)d_in[1];
    const float* attn_l = (const float*)d_in[2];
    const float* attn_r = (const float*)d_in[3];
    const float* bias   = (const float*)d_in[4];
    const int*   src    = (const int*)d_in[5];
    const int*   dst    = (const int*)d_in[6];
    const int*   etype  = (const int*)d_in[7];

    float* out_attn = (float*)d_out;                 // [E, 1, HEADS]
    float* out_ret  = out_attn + (size_t)EE * HEADS; // [N, FOUT]

    // workspace layout (bytes)
    char* ws = (char*)d_ws;
    unsigned short* nfh = (unsigned short*)(ws);     // 25.6 MB
    float* a1      = (float*)(ws + 25600000);        // 1.6 MB
    float* nt      = (float*)(ws + 27200000);        // 25.6 MB
    int*   deg     = (int*)(ws + 52800000);          // 200 KB
    int*   cursor  = (int*)(ws + 53000000);          // 200 KB
    int*   counter = (int*)(ws + 53200000);          // 128 B slot
    int*   rowptr  = (int*)(ws + 53200128);          // 200 KB
    int2*  recs    = (int2*)(ws + 53400192);         // 6.4 MB
    unsigned short* wall = (unsigned short*)(ws + 59800320);  // 102.4 KB

    // zero deg + cursor + counter (contiguous)
    hipMemsetAsync(deg, 0, (size_t)400128, stream);

    k_wallhist<<<WBLK + HBLK, 256, 0, stream>>>(fc_w, attn_l, attn_r, dst, wall, deg);

    k_alloc<<<ABLK, 256, 0, stream>>>(deg, counter, rowptr);

    k_scatgemm<<<GBLK + HBLK, 256, 0, stream>>>(x, wall, nfh, a1, nt,
                                                dst, src, etype, rowptr, cursor, recs);

    k_agg<<<(NN + 3) / 4, 256, 0, stream>>>(nfh, a1, nt, recs, rowptr, deg,
                                            bias, out_attn, out_ret);
}